// Round 10
// baseline (308.313 us; speedup 1.0000x reference)
//
#include <hip/hip_runtime.h>

typedef __attribute__((ext_vector_type(8))) short short8;
typedef __attribute__((ext_vector_type(4))) float f32x4;
typedef __attribute__((ext_vector_type(4))) unsigned short u16x4;

#define GLOAD16(g, l)                                                          \
  __builtin_amdgcn_global_load_lds(                                            \
      (const __attribute__((address_space(1))) unsigned int*)(g),              \
      (__attribute__((address_space(3))) unsigned int*)(l), 16, 0, 0)

__device__ __forceinline__ unsigned short f2bf(float f) {
  unsigned int u = __float_as_uint(f);
  u += 0x7FFFu + ((u >> 16) & 1u);   // RNE
  return (unsigned short)(u >> 16);
}
__device__ __forceinline__ float bf2f(unsigned short h) {
  return __uint_as_float(((unsigned int)h) << 16);
}

// ---------------------------------------------------------------- mix / bmix
__global__ void mix_kernel(const float* __restrict__ amp,
                           const float* __restrict__ phase,
                           const float* __restrict__ bias,
                           float* __restrict__ mix, float* __restrict__ bmix) {
  int q = blockIdx.x * blockDim.x + threadIdx.x;  // 0..1023
  float a[16];
  float mx = -1e30f;
  for (int s = 0; s < 16; ++s) {
    a[s] = amp[s * 1024 + q];
    mx = fmaxf(mx, a[s]);
  }
  float sum = 0.f;
  for (int s = 0; s < 16; ++s) {
    a[s] = __expf(a[s] - mx);
    sum += a[s];
  }
  float inv = 1.f / sum;
  for (int s = 0; s < 16; ++s) {
    float m = a[s] * inv * cosf(phase[s * 1024 + q]);
    mix[s * 1024 + q] = m;
    bmix[s * 1024 + q] = bias[s * 1024 + q] * m;
  }
}

// ---------------------------------------------------------------- cast x->bf16
__global__ void cast_x_kernel(const float* __restrict__ x,
                              unsigned short* __restrict__ xb) {
  int i = (blockIdx.x * blockDim.x + threadIdx.x) * 4;
  float4 v = *(const float4*)(x + i);
  union { unsigned short h[4]; uint2 u; } o;
  o.h[0] = f2bf(v.x); o.h[1] = f2bf(v.y); o.h[2] = f2bf(v.z); o.h[3] = f2bf(v.w);
  *(uint2*)(xb + i) = o.u;
}

// ------------------------------------------- transpose+cast+scale W -> Wt bf16
// Wt[s][q][i] = bf16( W[s][i][q] * mix[s][q] )
__global__ __launch_bounds__(256) void transpose_w_kernel(
    const float* __restrict__ W, const float* __restrict__ mix,
    unsigned short* __restrict__ Wt) {
  __shared__ unsigned short tile[64][66];
  const int s = blockIdx.z;
  const int q0 = blockIdx.x * 64, i0 = blockIdx.y * 64;
  const int t = threadIdx.x;
  const float* Ws = W + (size_t)s * 1048576;
  unsigned short* Wts = Wt + (size_t)s * 1048576;
  const int rq = t & 63, ri = t >> 6;
  const float mv = mix[s * 1024 + q0 + rq];
  #pragma unroll
  for (int p = 0; p < 16; ++p)
    tile[p * 4 + ri][rq] =
        f2bf(Ws[(size_t)(i0 + p * 4 + ri) * 1024 + q0 + rq] * mv);
  __syncthreads();
  const int wq = t >> 3, wi = (t & 7) * 8;
  #pragma unroll
  for (int o = 0; o < 2; ++o) {
    union { unsigned short h[8]; short8 v; } u;
    #pragma unroll
    for (int e = 0; e < 8; ++e) u.h[e] = tile[wi + e][o * 32 + wq];
    *(short8*)(Wts + (size_t)(q0 + o * 32 + wq) * 1024 + i0 + wi) = u.v;
  }
}

// ---------------------------------------------------------------- bf16 GEMM
// R9 pipeline + L2 supertiling: per-XCD 2D chunks of 4bx x 8by (resident set
// = 4 B-panels + 8 A-panels = 3MB < 4MB L2), bx-fast within chunk.  B-panel
// L3 refetch drops 8x, A 4x -> staging latency ~L2 (~200cy), covered by the
// depth-2 prefetch.  Mapping (bijective): xcd=bid&7, c=bid>>3, chunkg=
// (c>>5)*8+xcd, w=c&31, bx=(chunkg&31)*4+(w&3), by=(chunkg>>5)*8+(w>>2).
template <bool BF16SUP>
__global__ __launch_bounds__(256) void gemm_kernel(
    const unsigned short* __restrict__ xb, const unsigned short* __restrict__ wt,
    const float* __restrict__ bmix,
    float* __restrict__ outf, unsigned short* __restrict__ sup) {
  __shared__ __align__(16) unsigned short Abuf[3][128 * 32];
  __shared__ __align__(16) unsigned short Bbuf[3][128 * 32];

  const int tid = threadIdx.x;
  const int lane = tid & 63;
  const int wv = tid >> 6;
  const int wm = wv >> 1, wn = wv & 1;

  // L2-supertiled block mapping
  const int bid = blockIdx.x;
  const int xcd = bid & 7;
  const int c = bid >> 3;
  const int chunkg = (c >> 5) * 8 + xcd;   // 0..127
  const int w = c & 31;
  const int bx = (chunkg & 31) * 4 + (w & 3);
  const int by = (chunkg >> 5) * 8 + (w >> 2);
  const int m0 = by * 128;
  const int n0 = bx * 128;

  const int c0 = tid, c1 = tid + 256;
  const int r0 = c0 >> 2, k80 = (c0 & 3) * 8;
  const int r1 = c1 >> 2, k81 = (c1 & 3) * 8;
  const unsigned short* ga0 = xb + (size_t)(m0 + r0) * 1024 + k80;
  const unsigned short* ga1 = xb + (size_t)(m0 + r1) * 1024 + k81;
  const unsigned short* gb0 = wt + (size_t)(n0 + r0) * 1024 + k80;
  const unsigned short* gb1 = wt + (size_t)(n0 + r1) * 1024 + k81;

#define STAGE(kt, b) do {                                                      \
    const int _ko = (kt) * 32;                                                 \
    GLOAD16(ga0 + _ko, &Abuf[b][c0 * 8]);                                      \
    GLOAD16(ga1 + _ko, &Abuf[b][c1 * 8]);                                      \
    GLOAD16(gb0 + _ko, &Bbuf[b][c0 * 8]);                                      \
    GLOAD16(gb1 + _ko, &Bbuf[b][c1 * 8]);                                      \
  } while (0)

  f32x4 acc[4][4];
  #pragma unroll
  for (int i = 0; i < 4; ++i)
    #pragma unroll
    for (int j = 0; j < 4; ++j) acc[i][j] = (f32x4){0.f, 0.f, 0.f, 0.f};

  // prologue: stage tiles 0,1; wait tile 0 landed (tile 1 stays in flight)
  STAGE(0, 0);
  STAGE(1, 1);
  asm volatile("s_waitcnt vmcnt(4)" ::: "memory");
  __builtin_amdgcn_s_barrier();

  const int lr = lane & 15;
  const int lk = (lane >> 4) * 8;
  int cur = 0;
  for (int kt = 0; kt < 32; ++kt) {
    if (kt < 30) {
      int nb = cur + 2; if (nb >= 3) nb -= 3;
      STAGE(kt + 2, nb);
    }
    short8 af[4], bfr[4];
    #pragma unroll
    for (int mi = 0; mi < 4; ++mi)
      af[mi] = *(const short8*)&Abuf[cur][(wm * 64 + mi * 16 + lr) * 32 + lk];
    #pragma unroll
    for (int ni = 0; ni < 4; ++ni)
      bfr[ni] = *(const short8*)&Bbuf[cur][(wn * 64 + ni * 16 + lr) * 32 + lk];
    // drain my LDS reads, then wait next tile landed, then barrier (loads
    // for tile kt+2 remain in flight across it)
    asm volatile("s_waitcnt lgkmcnt(0)" ::: "memory");
    if (kt < 30) {
      asm volatile("s_waitcnt vmcnt(4)" ::: "memory");
    } else if (kt == 30) {
      asm volatile("s_waitcnt vmcnt(0)" ::: "memory");
    }
    __builtin_amdgcn_sched_barrier(0);
    __builtin_amdgcn_s_barrier();
    #pragma unroll
    for (int mi = 0; mi < 4; ++mi)
      #pragma unroll
      for (int ni = 0; ni < 4; ++ni)
        acc[mi][ni] = __builtin_amdgcn_mfma_f32_16x16x32_bf16(
            af[mi], bfr[ni], acc[mi][ni], 0, 0, 0);
    cur += 1; if (cur >= 3) cur = 0;
  }
#undef STAGE

  // epilogue: sup = acc + bmix  (mix folded into Wt)
  #pragma unroll
  for (int ni = 0; ni < 4; ++ni) {
    const int n = n0 + wn * 64 + ni * 16 + lr;
    const float bv = bmix[n];
    #pragma unroll
    for (int mi = 0; mi < 4; ++mi) {
      const int m = m0 + wm * 64 + mi * 16 + (lane >> 4) * 4;
      #pragma unroll
      for (int r = 0; r < 4; ++r) {
        float v = acc[mi][ni][r] + bv;
        if (BF16SUP)
          sup[(size_t)(m + r) * 16384 + n] = f2bf(v);
        else
          outf[(size_t)(m + r) * 16384 + n] = v;
      }
    }
  }
}

// ------------------------------------------------------- LN from bf16 sup
__global__ __launch_bounds__(256) void ln_bf16_kernel(
    const unsigned short* __restrict__ sup, float* __restrict__ out,
    const float* __restrict__ gamma, const float* __restrict__ beta) {
  __shared__ float red[8];
  const int t = threadIdx.x;
  const size_t base = (size_t)blockIdx.x * 1024;
  u16x4 raw = *(const u16x4*)(sup + base + t * 4);
  float v[4];
  #pragma unroll
  for (int j = 0; j < 4; ++j) v[j] = bf2f(raw[j]);
  float s = v[0] + v[1] + v[2] + v[3];
  float ss = v[0] * v[0] + v[1] * v[1] + v[2] * v[2] + v[3] * v[3];
  #pragma unroll
  for (int m = 32; m >= 1; m >>= 1) {
    s += __shfl_xor(s, m);
    ss += __shfl_xor(ss, m);
  }
  const int wv = t >> 6;
  if ((t & 63) == 0) { red[wv * 2] = s; red[wv * 2 + 1] = ss; }
  __syncthreads();
  const float S = red[0] + red[2] + red[4] + red[6];
  const float SS = red[1] + red[3] + red[5] + red[7];
  const float mean = S * (1.0f / 1024.0f);
  const float var = SS * (1.0f / 1024.0f) - mean * mean;
  const float rstd = rsqrtf(var + 1e-5f);
  const float4 g = *(const float4*)(gamma + t * 4);
  const float4 b = *(const float4*)(beta + t * 4);
  float4 o;
  o.x = (v[0] - mean) * rstd * g.x + b.x;
  o.y = (v[1] - mean) * rstd * g.y + b.y;
  o.z = (v[2] - mean) * rstd * g.z + b.z;
  o.w = (v[3] - mean) * rstd * g.w + b.w;
  *(float4*)(out + base + t * 4) = o;
}

// ------------------------------------------------------- in-place f32 LN
__global__ __launch_bounds__(256) void ln_kernel(float* __restrict__ out,
                                                 const float* __restrict__ gamma,
                                                 const float* __restrict__ beta) {
  __shared__ float red[8];
  const int t = threadIdx.x;
  const size_t base = (size_t)blockIdx.x * 1024;
  float4 v = *(const float4*)(out + base + t * 4);
  float s = v.x + v.y + v.z + v.w;
  float ss = v.x * v.x + v.y * v.y + v.z * v.z + v.w * v.w;
  #pragma unroll
  for (int m = 32; m >= 1; m >>= 1) {
    s += __shfl_xor(s, m);
    ss += __shfl_xor(ss, m);
  }
  const int wv = t >> 6;
  if ((t & 63) == 0) { red[wv * 2] = s; red[wv * 2 + 1] = ss; }
  __syncthreads();
  const float S = red[0] + red[2] + red[4] + red[6];
  const float SS = red[1] + red[3] + red[5] + red[7];
  const float mean = S * (1.0f / 1024.0f);
  const float var = SS * (1.0f / 1024.0f) - mean * mean;
  const float rstd = rsqrtf(var + 1e-5f);
  const float4 g = *(const float4*)(gamma + t * 4);
  const float4 b = *(const float4*)(beta + t * 4);
  float4 o;
  o.x = (v.x - mean) * rstd * g.x + b.x;
  o.y = (v.y - mean) * rstd * g.y + b.y;
  o.z = (v.z - mean) * rstd * g.z + b.z;
  o.w = (v.w - mean) * rstd * g.w + b.w;
  *(float4*)(out + base + t * 4) = o;
}

extern "C" void kernel_launch(void* const* d_in, const int* in_sizes, int n_in,
                              void* d_out, int out_size, void* d_ws, size_t ws_size,
                              hipStream_t stream) {
  (void)in_sizes; (void)n_in; (void)out_size;
  const float* x     = (const float*)d_in[0];  // [4096,1024]
  const float* W     = (const float*)d_in[1];  // [16,1024,1024]
  const float* bias  = (const float*)d_in[2];  // [16,1024]
  const float* amp   = (const float*)d_in[3];  // [16,1024]
  const float* phase = (const float*)d_in[4];  // [16,1024]
  const float* gamma = (const float*)d_in[5];  // [1024]
  const float* beta  = (const float*)d_in[6];  // [1024]
  float* out = (float*)d_out;                  // [4096,16,1024] = 256 MiB

  const bool big = ws_size >= (size_t)134217728ULL;  // bf16 sup fits in ws

  unsigned short *Wt, *xbuf, *supb = nullptr;
  float *mixp, *bmixp;
  if (big) {
    // scratch Wt/xb/mix live in d_out (fully rewritten by LN afterwards);
    // ws holds bf16 sup (exactly 128 MiB)
    char* ob = (char*)d_out;
    Wt    = (unsigned short*)ob;                    // 32 MiB
    xbuf  = (unsigned short*)(ob + 33554432);       //  8 MiB
    mixp  = (float*)(ob + 41943040);                // 64 KiB
    bmixp = mixp + 16384;                           // 64 KiB
    supb  = (unsigned short*)d_ws;                  // 128 MiB
  } else {
    char* ws = (char*)d_ws;
    Wt    = (unsigned short*)ws;
    xbuf  = (unsigned short*)(ws + 33554432);
    mixp  = (float*)(ws + 33554432 + 8388608);
    bmixp = mixp + 16384;
  }

  hipLaunchKernelGGL(mix_kernel, dim3(4), dim3(256), 0, stream, amp, phase, bias, mixp, bmixp);
  hipLaunchKernelGGL(cast_x_kernel, dim3(4096), dim3(256), 0, stream, x, xbuf);
  hipLaunchKernelGGL(transpose_w_kernel, dim3(16, 16, 16), dim3(256), 0, stream, W, mixp, Wt);
  if (big) {
    hipLaunchKernelGGL((gemm_kernel<true>), dim3(4096), dim3(256), 0, stream,
                       xbuf, Wt, bmixp, out, supb);
    hipLaunchKernelGGL(ln_bf16_kernel, dim3(65536), dim3(256), 0, stream,
                       supb, out, gamma, beta);
  } else {
    hipLaunchKernelGGL((gemm_kernel<false>), dim3(4096), dim3(256), 0, stream,
                       xbuf, Wt, bmixp, out, nullptr);
    hipLaunchKernelGGL(ln_kernel, dim3(65536), dim3(256), 0, stream, out, gamma, beta);
  }
}

// Round 12
// 299.599 us; speedup vs baseline: 1.0291x; 1.0291x over previous
//
#include <hip/hip_runtime.h>

typedef __attribute__((ext_vector_type(8))) short short8;
typedef __attribute__((ext_vector_type(4))) float f32x4;
typedef __attribute__((ext_vector_type(4))) unsigned short u16x4;

#define GLOAD16(g, l)                                                          \
  __builtin_amdgcn_global_load_lds(                                            \
      (const __attribute__((address_space(1))) unsigned int*)(g),              \
      (__attribute__((address_space(3))) unsigned int*)(l), 16, 0, 0)

__device__ __forceinline__ unsigned short f2bf(float f) {
  unsigned int u = __float_as_uint(f);
  u += 0x7FFFu + ((u >> 16) & 1u);   // RNE
  return (unsigned short)(u >> 16);
}
__device__ __forceinline__ float bf2f(unsigned short h) {
  return __uint_as_float(((unsigned int)h) << 16);
}

// ---------------------------------------------------------------- mix / bmix
__global__ void mix_kernel(const float* __restrict__ amp,
                           const float* __restrict__ phase,
                           const float* __restrict__ bias,
                           float* __restrict__ mix, float* __restrict__ bmix) {
  int q = blockIdx.x * blockDim.x + threadIdx.x;  // 0..1023
  float a[16];
  float mx = -1e30f;
  for (int s = 0; s < 16; ++s) {
    a[s] = amp[s * 1024 + q];
    mx = fmaxf(mx, a[s]);
  }
  float sum = 0.f;
  for (int s = 0; s < 16; ++s) {
    a[s] = __expf(a[s] - mx);
    sum += a[s];
  }
  float inv = 1.f / sum;
  for (int s = 0; s < 16; ++s) {
    float m = a[s] * inv * cosf(phase[s * 1024 + q]);
    mix[s * 1024 + q] = m;
    bmix[s * 1024 + q] = bias[s * 1024 + q] * m;
  }
}

// ---------------------------------------------------------------- cast x->bf16
__global__ void cast_x_kernel(const float* __restrict__ x,
                              unsigned short* __restrict__ xb) {
  int i = (blockIdx.x * blockDim.x + threadIdx.x) * 4;
  float4 v = *(const float4*)(x + i);
  union { unsigned short h[4]; uint2 u; } o;
  o.h[0] = f2bf(v.x); o.h[1] = f2bf(v.y); o.h[2] = f2bf(v.z); o.h[3] = f2bf(v.w);
  *(uint2*)(xb + i) = o.u;
}

// ------------------------------------------- transpose+cast+scale W -> Wt bf16
// Wt[s][q][i] = bf16( W[s][i][q] * mix[s][q] ).  float4 reads (16B/lane),
// packed uint2 LDS writes, short8 global writes (128B contiguous per q-row).
__global__ __launch_bounds__(256) void transpose_w_kernel(
    const float* __restrict__ W, const float* __restrict__ mix,
    unsigned short* __restrict__ Wt) {
  __shared__ unsigned short tile[64][68];   // 68-short row = 17 dwords, coprime 32
  const int s = blockIdx.z;
  const int q0 = blockIdx.x * 64, i0 = blockIdx.y * 64;
  const int t = threadIdx.x;
  const float* Ws = W + (size_t)s * 1048576;
  unsigned short* Wts = Wt + (size_t)s * 1048576;
  const int rq = (t & 15) * 4;
  const int ri = t >> 4;                    // 0..15
  const float4 mv = *(const float4*)(mix + s * 1024 + q0 + rq);
  #pragma unroll
  for (int p = 0; p < 4; ++p) {
    const int i = p * 16 + ri;
    float4 v = *(const float4*)(Ws + (size_t)(i0 + i) * 1024 + q0 + rq);
    union { unsigned short h[4]; uint2 u; } pk;
    pk.h[0] = f2bf(v.x * mv.x);
    pk.h[1] = f2bf(v.y * mv.y);
    pk.h[2] = f2bf(v.z * mv.z);
    pk.h[3] = f2bf(v.w * mv.w);
    *(uint2*)&tile[i][rq] = pk.u;
  }
  __syncthreads();
  const int wq = t >> 2;                    // 0..63
  const int wi = (t & 3) * 16;              // 0,16,32,48
  union { unsigned short h[8]; short8 v8; } u0, u1;
  #pragma unroll
  for (int e = 0; e < 8; ++e) {
    u0.h[e] = tile[wi + e][wq];
    u1.h[e] = tile[wi + 8 + e][wq];
  }
  unsigned short* dst = Wts + (size_t)(q0 + wq) * 1024 + i0 + wi;
  *(short8*)dst = u0.v8;
  *(short8*)(dst + 8) = u1.v8;
}

// ---------------------------------------------------------------- bf16 GEMM
// R9 (best: 185us) + register ds_read prefetch (R11 with the buffer-rotation
// bug fixed: tiles advance TWO per iteration => b0 = b2, not b1).
// Reads for tile kt+1 issue right after the barrier; MFMA(kt) covers their
// LDS latency; lgkmcnt(0) waits them only at the NEXT sub-step.
// Ledger (b0 = 2it%3): STAGE(kt0+2,b2) ✓; READS(b1)=kt1 ✓ (post vmcnt(4)+bar);
// STAGE(kt1+2,b0) ✓ ((2it+3)%3 = b0, prior b0 reads drained >=1 barrier ago);
// READS(b2)=kt0+2 ✓.  Tail it=15: vmcnt(0) at kt0=30; no read at kt1=31.
template <bool BF16SUP>
__global__ __launch_bounds__(256) void gemm_kernel(
    const unsigned short* __restrict__ xb, const unsigned short* __restrict__ wt,
    const float* __restrict__ bmix,
    float* __restrict__ outf, unsigned short* __restrict__ sup) {
  __shared__ __align__(16) unsigned short Abuf[3][128 * 32];
  __shared__ __align__(16) unsigned short Bbuf[3][128 * 32];

  const int tid = threadIdx.x;
  const int lane = tid & 63;
  const int wv = tid >> 6;
  const int wm = wv >> 1, wn = wv & 1;
  const int m0 = blockIdx.y * 128;
  const int n0 = blockIdx.x * 128;

  const int c0 = tid, c1 = tid + 256;
  const int r0 = c0 >> 2, k80 = (c0 & 3) * 8;
  const int r1 = c1 >> 2, k81 = (c1 & 3) * 8;
  const unsigned short* ga0 = xb + (size_t)(m0 + r0) * 1024 + k80;
  const unsigned short* ga1 = xb + (size_t)(m0 + r1) * 1024 + k81;
  const unsigned short* gb0 = wt + (size_t)(n0 + r0) * 1024 + k80;
  const unsigned short* gb1 = wt + (size_t)(n0 + r1) * 1024 + k81;

#define STAGE(kt, b) do {                                                      \
    const int _ko = (kt) * 32;                                                 \
    GLOAD16(ga0 + _ko, &Abuf[b][c0 * 8]);                                      \
    GLOAD16(ga1 + _ko, &Abuf[b][c1 * 8]);                                      \
    GLOAD16(gb0 + _ko, &Bbuf[b][c0 * 8]);                                      \
    GLOAD16(gb1 + _ko, &Bbuf[b][c1 * 8]);                                      \
  } while (0)

  f32x4 acc[4][4];
  #pragma unroll
  for (int i = 0; i < 4; ++i)
    #pragma unroll
    for (int j = 0; j < 4; ++j) acc[i][j] = (f32x4){0.f, 0.f, 0.f, 0.f};

  const int lr = lane & 15;
  const int lk = (lane >> 4) * 8;

#define READS(AF, BF, b) do {                                                  \
    const unsigned short* _ab = &Abuf[b][(wm * 64 + lr) * 32 + lk];            \
    _Pragma("unroll")                                                          \
    for (int mi = 0; mi < 4; ++mi)                                             \
      AF[mi] = *(const short8*)(_ab + mi * 16 * 32);                           \
    const unsigned short* _bb = &Bbuf[b][(wn * 64 + lr) * 32 + lk];            \
    _Pragma("unroll")                                                          \
    for (int ni = 0; ni < 4; ++ni)                                             \
      BF[ni] = *(const short8*)(_bb + ni * 16 * 32);                           \
  } while (0)

#define MFMASET(AF, BF)                                                        \
    _Pragma("unroll")                                                          \
    for (int mi = 0; mi < 4; ++mi)                                             \
      _Pragma("unroll")                                                        \
      for (int ni = 0; ni < 4; ++ni)                                           \
        acc[mi][ni] = __builtin_amdgcn_mfma_f32_16x16x32_bf16(                 \
            AF[mi], BF[ni], acc[mi][ni], 0, 0, 0)

#define LGKM0() do { asm volatile("s_waitcnt lgkmcnt(0)" ::: "memory");        \
                     __builtin_amdgcn_sched_barrier(0); } while (0)

  short8 afA[4], bfA[4], afB[4], bfB[4];

  // prologue: stage tiles 0,1; wait tile 0 landed; read tile 0 into set A
  STAGE(0, 0);
  STAGE(1, 1);
  asm volatile("s_waitcnt vmcnt(4)" ::: "memory");
  __builtin_amdgcn_s_barrier();
  READS(afA, bfA, 0);

  int b0 = 0;   // buffer of tile kt0 (= 2*it mod 3)
  #pragma unroll 1
  for (int it = 0; it < 16; ++it) {
    const int kt0 = 2 * it, kt1 = kt0 + 1;
    int b1 = b0 + 1; if (b1 >= 3) b1 -= 3;
    int b2 = b0 + 2; if (b2 >= 3) b2 -= 3;
    // --- sub-step A: compute kt0 (set A), prefetch-read kt1 into set B
    if (kt0 < 30) STAGE(kt0 + 2, b2);
    LGKM0();                                     // set-A reads complete
    if (kt0 < 30) asm volatile("s_waitcnt vmcnt(4)" ::: "memory");
    else          asm volatile("s_waitcnt vmcnt(0)" ::: "memory");
    __builtin_amdgcn_sched_barrier(0);
    __builtin_amdgcn_s_barrier();                // tile kt1 valid block-wide
    READS(afB, bfB, b1);                         // issue only; MFMA covers
    MFMASET(afA, bfA);
    // --- sub-step B: compute kt1 (set B), prefetch kt0+2 into set A
    if (kt1 < 30) STAGE(kt1 + 2, b0);            // (kt1+2)%3 == b0
    LGKM0();                                     // set-B reads complete
    if (kt1 < 30) asm volatile("s_waitcnt vmcnt(4)" ::: "memory");
    __builtin_amdgcn_sched_barrier(0);
    __builtin_amdgcn_s_barrier();
    if (kt1 < 31) READS(afA, bfA, b2);           // tile kt0+2 in buf b2
    MFMASET(afB, bfB);
    b0 = b2;   // tiles advance by 2 per iteration (FIX vs R11)
  }
#undef STAGE
#undef READS
#undef MFMASET
#undef LGKM0

  // epilogue: sup = acc + bmix  (mix folded into Wt)
  #pragma unroll
  for (int ni = 0; ni < 4; ++ni) {
    const int n = n0 + wn * 64 + ni * 16 + lr;
    const float bv = bmix[n];
    #pragma unroll
    for (int mi = 0; mi < 4; ++mi) {
      const int m = m0 + wm * 64 + mi * 16 + (lane >> 4) * 4;
      #pragma unroll
      for (int r = 0; r < 4; ++r) {
        float v = acc[mi][ni][r] + bv;
        if (BF16SUP)
          sup[(size_t)(m + r) * 16384 + n] = f2bf(v);
        else
          outf[(size_t)(m + r) * 16384 + n] = v;
      }
    }
  }
}

// ------------------------------------------------------- LN from bf16 sup
__global__ __launch_bounds__(256) void ln_bf16_kernel(
    const unsigned short* __restrict__ sup, float* __restrict__ out,
    const float* __restrict__ gamma, const float* __restrict__ beta) {
  __shared__ float red[8];
  const int t = threadIdx.x;
  const size_t base = (size_t)blockIdx.x * 1024;
  u16x4 raw = *(const u16x4*)(sup + base + t * 4);
  float v[4];
  #pragma unroll
  for (int j = 0; j < 4; ++j) v[j] = bf2f(raw[j]);
  float s = v[0] + v[1] + v[2] + v[3];
  float ss = v[0] * v[0] + v[1] * v[1] + v[2] * v[2] + v[3] * v[3];
  #pragma unroll
  for (int m = 32; m >= 1; m >>= 1) {
    s += __shfl_xor(s, m);
    ss += __shfl_xor(ss, m);
  }
  const int wv = t >> 6;
  if ((t & 63) == 0) { red[wv * 2] = s; red[wv * 2 + 1] = ss; }
  __syncthreads();
  const float S = red[0] + red[2] + red[4] + red[6];
  const float SS = red[1] + red[3] + red[5] + red[7];
  const float mean = S * (1.0f / 1024.0f);
  const float var = SS * (1.0f / 1024.0f) - mean * mean;
  const float rstd = rsqrtf(var + 1e-5f);
  const float4 g = *(const float4*)(gamma + t * 4);
  const float4 b = *(const float4*)(beta + t * 4);
  float4 o;
  o.x = (v[0] - mean) * rstd * g.x + b.x;
  o.y = (v[1] - mean) * rstd * g.y + b.y;
  o.z = (v[2] - mean) * rstd * g.z + b.z;
  o.w = (v[3] - mean) * rstd * g.w + b.w;
  *(float4*)(out + base + t * 4) = o;
}

// ------------------------------------------------------- in-place f32 LN
__global__ __launch_bounds__(256) void ln_kernel(float* __restrict__ out,
                                                 const float* __restrict__ gamma,
                                                 const float* __restrict__ beta) {
  __shared__ float red[8];
  const int t = threadIdx.x;
  const size_t base = (size_t)blockIdx.x * 1024;
  float4 v = *(const float4*)(out + base + t * 4);
  float s = v.x + v.y + v.z + v.w;
  float ss = v.x * v.x + v.y * v.y + v.z * v.z + v.w * v.w;
  #pragma unroll
  for (int m = 32; m >= 1; m >>= 1) {
    s += __shfl_xor(s, m);
    ss += __shfl_xor(ss, m);
  }
  const int wv = t >> 6;
  if ((t & 63) == 0) { red[wv * 2] = s; red[wv * 2 + 1] = ss; }
  __syncthreads();
  const float S = red[0] + red[2] + red[4] + red[6];
  const float SS = red[1] + red[3] + red[5] + red[7];
  const float mean = S * (1.0f / 1024.0f);
  const float var = SS * (1.0f / 1024.0f) - mean * mean;
  const float rstd = rsqrtf(var + 1e-5f);
  const float4 g = *(const float4*)(gamma + t * 4);
  const float4 b = *(const float4*)(beta + t * 4);
  float4 o;
  o.x = (v.x - mean) * rstd * g.x + b.x;
  o.y = (v.y - mean) * rstd * g.y + b.y;
  o.z = (v.z - mean) * rstd * g.z + b.z;
  o.w = (v.w - mean) * rstd * g.w + b.w;
  *(float4*)(out + base + t * 4) = o;
}

extern "C" void kernel_launch(void* const* d_in, const int* in_sizes, int n_in,
                              void* d_out, int out_size, void* d_ws, size_t ws_size,
                              hipStream_t stream) {
  (void)in_sizes; (void)n_in; (void)out_size;
  const float* x     = (const float*)d_in[0];  // [4096,1024]
  const float* W     = (const float*)d_in[1];  // [16,1024,1024]
  const float* bias  = (const float*)d_in[2];  // [16,1024]
  const float* amp   = (const float*)d_in[3];  // [16,1024]
  const float* phase = (const float*)d_in[4];  // [16,1024]
  const float* gamma = (const float*)d_in[5];  // [1024]
  const float* beta  = (const float*)d_in[6];  // [1024]
  float* out = (float*)d_out;                  // [4096,16,1024] = 256 MiB

  const bool big = ws_size >= (size_t)134217728ULL;  // bf16 sup fits in ws

  unsigned short *Wt, *xbuf, *supb = nullptr;
  float *mixp, *bmixp;
  if (big) {
    // scratch Wt/xb/mix live in d_out (fully rewritten by LN afterwards);
    // ws holds bf16 sup (exactly 128 MiB)
    char* ob = (char*)d_out;
    Wt    = (unsigned short*)ob;                    // 32 MiB
    xbuf  = (unsigned short*)(ob + 33554432);       //  8 MiB
    mixp  = (float*)(ob + 41943040);                // 64 KiB
    bmixp = mixp + 16384;                           // 64 KiB
    supb  = (unsigned short*)d_ws;                  // 128 MiB
  } else {
    char* ws = (char*)d_ws;
    Wt    = (unsigned short*)ws;
    xbuf  = (unsigned short*)(ws + 33554432);
    mixp  = (float*)(ws + 33554432 + 8388608);
    bmixp = mixp + 16384;
  }

  hipLaunchKernelGGL(mix_kernel, dim3(4), dim3(256), 0, stream, amp, phase, bias, mixp, bmixp);
  hipLaunchKernelGGL(cast_x_kernel, dim3(4096), dim3(256), 0, stream, x, xbuf);
  hipLaunchKernelGGL(transpose_w_kernel, dim3(16, 16, 16), dim3(256), 0, stream, W, mixp, Wt);
  if (big) {
    hipLaunchKernelGGL((gemm_kernel<true>), dim3(128, 32), dim3(256), 0, stream,
                       xbuf, Wt, bmixp, out, supb);
    hipLaunchKernelGGL(ln_bf16_kernel, dim3(65536), dim3(256), 0, stream,
                       supb, out, gamma, beta);
  } else {
    hipLaunchKernelGGL((gemm_kernel<false>), dim3(128, 32), dim3(256), 0, stream,
                       xbuf, Wt, bmixp, out, nullptr);
    hipLaunchKernelGGL(ln_kernel, dim3(65536), dim3(256), 0, stream, out, gamma, beta);
  }
}